// Round 21
// baseline (528.392 us; speedup 1.0000x reference)
//
#include <hip/hip_runtime.h>
#include <hip/hip_fp16.h>
#include <math.h>

#define HD 256
#define NHEAD 4
#define CH 64
#define NLAYER 3
#define NEG_SLOPE 0.2f

typedef __attribute__((ext_vector_type(8))) _Float16 half8;
typedef __attribute__((ext_vector_type(4))) _Float16 half4v;
typedef __attribute__((ext_vector_type(4))) float float4v;
typedef __attribute__((ext_vector_type(4))) unsigned uint4v;

// ---------------------------------------------------------------------------
// FUSED: node embed (blocks [0, embedBlocks)) + degree count (rest).
// h0 = x @ Wn + bn_b  (fp16 out);  deg[col[e]]++ via atomics.
// ---------------------------------------------------------------------------
__global__ __launch_bounds__(256) void embed_count_kernel(
    const float* __restrict__ x, const float* __restrict__ Wn,
    const float* __restrict__ bn_b, _Float16* __restrict__ h, int N,
    const int* __restrict__ col, int* __restrict__ deg, int E,
    int embedBlocks) {
  int tid = threadIdx.x;
  if ((int)blockIdx.x < embedBlocks) {
    int base = blockIdx.x * 8;
    __shared__ float xs[8][9];
    int nn = N - base;
    if (nn > 8) nn = 8;
    if (tid < nn * 9) xs[tid / 9][tid % 9] = x[(size_t)base * 9 + tid];
    __syncthreads();
    float b = bn_b[tid];
    for (int i = 0; i < nn; ++i) {
      float v = b;
#pragma unroll
      for (int k = 0; k < 9; ++k) v += xs[i][k] * Wn[k * HD + tid];
      h[(size_t)(base + i) * HD + tid] = (_Float16)v;
    }
  } else {
    int e = (blockIdx.x - embedBlocks) * 256 + tid;
    if (e < E) atomicAdd(&deg[col[e]], 1);
  }
}

// ---------------------------------------------------------------------------
// FUSED: precompute_wc (blocks 0..11) + conv_bfrag (blocks 12..).
// ---------------------------------------------------------------------------
__global__ __launch_bounds__(256) void wc_bfrag_kernel(
    const float* __restrict__ lin_edge_w, const float* __restrict__ att_edge,
    const float* __restrict__ We, const float* __restrict__ be_b,
    float* __restrict__ Wc, float* __restrict__ bc,
    const float* __restrict__ lin_w, _Float16* __restrict__ Bf_hi) {
  int tid = threadIdx.x;
  if (blockIdx.x < 12) {
    int lh = blockIdx.x;           // l*4+hh
    int l = lh >> 2, hh = lh & 3;
    __shared__ float weff[256];
    int j = tid;
    const float* lw = lin_edge_w + (size_t)l * HD * HD + (size_t)j * HD + hh * CH;
    const float* ae = att_edge + l * HD + hh * CH;
    float s = 0.f;
#pragma unroll 8
    for (int c = 0; c < CH; ++c) s += lw[c] * ae[c];
    weff[j] = s;
    __syncthreads();
    if (j < 5) {
      float acc = 0.f;
      for (int t = 0; t < 256; ++t) acc += We[j * HD + t] * weff[t];
      Wc[j * 12 + lh] = acc;
    } else if (j == 5) {
      float acc = 0.f;
      for (int t = 0; t < 256; ++t) acc += be_b[t] * weff[t];
      bc[lh] = acc;
    }
  } else {
    int bid = (blockIdx.x - 12) * 4 + (tid >> 6);  // l*128 + kt*16 + ntg
    int l = bid >> 7;
    int kt = (bid >> 4) & 7, ntg = bid & 15;
    int lane = tid & 63;
    const float* B = lin_w + (size_t)l * HD * HD;
    size_t base = ((size_t)bid * 64 + lane) * 8;
    int k0 = kt * 32 + (lane >> 4) * 8;
    int n = ((ntg >= 8) ? 128 : 0) + (lane & 15) * 8 + (ntg & 7);
#pragma unroll
    for (int j = 0; j < 8; ++j) {
      Bf_hi[base + j] = (_Float16)B[(size_t)(k0 + j) * HD + n];
    }
  }
}

// ---------------------------------------------------------------------------
// CSR scan kernels
// ---------------------------------------------------------------------------
__global__ __launch_bounds__(256) void tile_sums_kernel(
    const int* __restrict__ deg, int* __restrict__ tsum, int N) {
  __shared__ int red[256];
  int i = blockIdx.x * 256 + threadIdx.x;
  red[threadIdx.x] = (i < N) ? deg[i] : 0;
  __syncthreads();
  for (int off = 128; off > 0; off >>= 1) {
    if (threadIdx.x < off) red[threadIdx.x] += red[threadIdx.x + off];
    __syncthreads();
  }
  if (threadIdx.x == 0) tsum[blockIdx.x] = red[0];
}

__global__ __launch_bounds__(64) void scan_tsums_kernel(
    const int* __restrict__ tsum, int* __restrict__ toff, int T) {
  int lane = threadIdx.x;
  int carry = 0;
  for (int base = 0; base < T; base += 64) {
    int i = base + lane;
    int orig = (i < T) ? tsum[i] : 0;
    int v = orig;
#pragma unroll
    for (int off = 1; off < 64; off <<= 1) {
      int t = __shfl_up(v, off, 64);
      if (lane >= off) v += t;
    }
    if (i < T) toff[i] = carry + v - orig;
    carry += __shfl(v, 63, 64);
  }
}

__global__ __launch_bounds__(256) void scan_local_kernel(
    const int* __restrict__ deg, const int* __restrict__ toff,
    int* __restrict__ row_start, int N, int E) {
  __shared__ int buf[256];
  int i = blockIdx.x * 256 + threadIdx.x;
  int v = (i < N) ? deg[i] : 0;
  buf[threadIdx.x] = v;
  __syncthreads();
  for (int off = 1; off < 256; off <<= 1) {
    int t = (threadIdx.x >= off) ? buf[threadIdx.x - off] : 0;
    __syncthreads();
    buf[threadIdx.x] += t;
    __syncthreads();
  }
  if (i < N) row_start[i] = toff[blockIdx.x] + buf[threadIdx.x] - v;
  if (blockIdx.x == 0 && threadIdx.x == 0) row_start[N] = E;
}

// ---------------------------------------------------------------------------
// CSR scatter writing ONE 32B record per edge via NON-TEMPORAL stores
// (native ext_vector uint4v — HIP's uint4 class is rejected by the builtin):
// word0 = src row, words 1..6 = 12 x fp16 a_e, word7 pad.
// ---------------------------------------------------------------------------
__global__ __launch_bounds__(256) void scatter_csr_ae_kernel(
    const int* __restrict__ row, const int* __restrict__ col,
    const float* __restrict__ edge_attr, const int* __restrict__ row_start,
    int* __restrict__ cursor, const float* __restrict__ Wc,
    const float* __restrict__ bc, unsigned* __restrict__ ecsr, int E) {
  __shared__ float sWc[60];
  __shared__ float sbc[12];
  int t = threadIdx.x;
  if (t < 60) sWc[t] = Wc[t];
  if (t < 12) sbc[t] = bc[t];
  __syncthreads();
  int e = blockIdx.x * 256 + t;
  if (e >= E) return;
  int c = col[e];
  int p = atomicAdd(&cursor[c], 1);
  float ea[5];
#pragma unroll
  for (int k = 0; k < 5; ++k) ea[k] = edge_attr[(size_t)e * 5 + k];
  unsigned rec[8];
  rec[0] = (unsigned)row[e];
#pragma unroll
  for (int l = 0; l < NLAYER; ++l) {
    float av[NHEAD];
#pragma unroll
    for (int hh = 0; hh < NHEAD; ++hh) {
      int lh = l * NHEAD + hh;
      float s = sbc[lh];
#pragma unroll
      for (int k = 0; k < 5; ++k) s += ea[k] * sWc[k * 12 + lh];
      av[hh] = s;
    }
    __half2 p0 = __floats2half2_rn(av[0], av[1]);
    __half2 p1 = __floats2half2_rn(av[2], av[3]);
    rec[1 + 2 * l] = *(unsigned*)&p0;
    rec[2 + 2 * l] = *(unsigned*)&p1;
  }
  rec[7] = 0u;
  int slot = row_start[c] + p;
  uint4v* dst = (uint4v*)(ecsr + (size_t)slot * 8);
  uint4v v0 = {rec[0], rec[1], rec[2], rec[3]};
  uint4v v1 = {rec[4], rec[5], rec[6], rec[7]};
  __builtin_nontemporal_store(v0, dst);
  __builtin_nontemporal_store(v1, dst + 1);
}

// ---------------------------------------------------------------------------
// MFMA GEMM — A fp16: direct half8 load, 1 MFMA per (kt,nt).
// Head-split grid y, 8KB LDS B-stage.
// ---------------------------------------------------------------------------
__global__ __launch_bounds__(512) void mfma_gemm_fused_kernel(
    const _Float16* __restrict__ A, const _Float16* __restrict__ Bf_hi,
    const float* __restrict__ att_s, const float* __restrict__ att_d,
    __half* __restrict__ xh_h, float* __restrict__ a_src,
    float* __restrict__ a_dst, int N) {
  __shared__ _Float16 sBh[4096];  // 8 KB: kt-slice of this block's col half
  const int tid = threadIdx.x;
  const int wave = tid >> 6, lane = tid & 63;
  const int m = lane & 15, quad = lane >> 4;
  const int y = blockIdx.y;
  const int rowbase = blockIdx.x * 128 + wave * 16;
  const int arow = rowbase + m;
  const int arowc = (arow < N) ? arow : (N - 1);

  float4v acc[8];
#pragma unroll
  for (int nt = 0; nt < 8; ++nt) acc[nt] = (float4v){0.f, 0.f, 0.f, 0.f};

  for (int kt = 0; kt < 8; ++kt) {
    __syncthreads();  // previous iteration's LDS reads done
    {
      const float4* gh = (const float4*)(Bf_hi + ((size_t)kt * 16 + y * 8) * 512);
      ((float4*)sBh)[tid] = gh[tid];
    }
    half8 a = *(const half8*)(A + (size_t)arowc * HD + kt * 32 + quad * 8);
    __syncthreads();  // staging complete
#pragma unroll
    for (int nt = 0; nt < 8; ++nt) {
      half8 bhi = *(const half8*)&sBh[nt * 512 + lane * 8];
      acc[nt] = __builtin_amdgcn_mfma_f32_16x16x32_f16(a, bhi, acc[nt], 0, 0, 0);
    }
  }

  // lane's 8 cols: y*128 + m*8 + nt — all in head hh = y*2 + (m>>3)
  const int hh = y * 2 + (m >> 3);
  const int colbase = y * 128 + m * 8;
  float ats[8], atd[8];
#pragma unroll
  for (int nt = 0; nt < 8; ++nt) {
    ats[nt] = att_s[colbase + nt];
    atd[nt] = att_d[colbase + nt];
  }
  _Float16* xf = (_Float16*)xh_h;
#pragma unroll
  for (int r = 0; r < 4; ++r) {
    int orow = rowbase + quad * 4 + r;
    bool valid = orow < N;
    float ps = 0.f, pd = 0.f;
    half8 h0;
#pragma unroll
    for (int nt = 0; nt < 8; ++nt) {
      h0[nt] = (_Float16)acc[nt][r];
      ps += acc[nt][r] * ats[nt];
      pd += acc[nt][r] * atd[nt];
    }
    if (valid) {
      *(half8*)(xf + (size_t)orow * HD + colbase) = h0;
    }
    ps += __shfl_xor(ps, 1, 64);
    ps += __shfl_xor(ps, 2, 64);
    ps += __shfl_xor(ps, 4, 64);
    pd += __shfl_xor(pd, 1, 64);
    pd += __shfl_xor(pd, 2, 64);
    pd += __shfl_xor(pd, 4, 64);
    if (valid && (m & 7) == 0) {
      a_src[(size_t)orow * NHEAD + hh] = ps;
      a_dst[(size_t)orow * NHEAD + hh] = pd;
    }
  }
}

// ---------------------------------------------------------------------------
// SINGLE-PASS fused softmax + gather-aggregate over 32B edge records.
// (R19 counters: ~6.2 TB/s effective — at the measured streaming ceiling.)
// ---------------------------------------------------------------------------
__global__ __launch_bounds__(256) void fused_aggregate_kernel(
    const __half* __restrict__ xh_h, const unsigned* __restrict__ ecsr,
    const int* __restrict__ row_start, int lsel,
    const float* __restrict__ a_src, const float* __restrict__ a_dst,
    const float* __restrict__ cb, const float* __restrict__ gm,
    const float* __restrict__ bt, float inv_std, _Float16* __restrict__ hout,
    int N) {
  int tid = threadIdx.x;
  int n = blockIdx.x * 4 + (tid >> 6);
  if (n >= N) return;
  int lane = tid & 63;
  int s = row_start[n], e = row_start[n + 1];

  const int hw = lane >> 4;        // head (same for weights and channels)
  const int eidx = lane & 15;
  const int t = lane;              // half4 index (4 ch/lane)
  const int ch = t * 4;
  const half4v* xh4 = (const half4v*)xh_h;
  const float based = a_dst[n * 4 + hw];
  const int aofs = 1 + 2 * lsel + (hw >> 1);
  const bool hi_half = (hw & 1);

  float a0 = 0.f, a1 = 0.f, a2 = 0.f, a3 = 0.f;
  float zpart = 0.f, aepart = 0.f;

  const int base_src = lane & 48;
  for (int chunk = s; chunk < e; chunk += 16) {
    int myedge = chunk + eidx;
    int r_my = 0;
    float w_my = 0.f;
    if (myedge < e) {
      const unsigned* rp = ecsr + (size_t)myedge * 8;
      r_my = (int)rp[0];
      unsigned aw = rp[aofs];
      __half2 h2 = *(__half2*)&aw;
      float ae = hi_half ? __high2float(h2) : __low2float(h2);
      float lg = a_src[r_my * 4 + hw] + based + ae;
      lg = (lg >= 0.f) ? lg : NEG_SLOPE * lg;
      w_my = __expf(lg);
      zpart += w_my;
      aepart += ae;
    }
#pragma unroll
    for (int u = 0; u < 16; ++u) {
      float w = __shfl(w_my, base_src + u, 64);
      int ru = __shfl(r_my, base_src + u, 64);
      half4v xv = xh4[(size_t)ru * 64 + t];
      a0 += w * (float)xv[0];
      a1 += w * (float)xv[1];
      a2 += w * (float)xv[2];
      a3 += w * (float)xv[3];
    }
  }
#pragma unroll
  for (int off = 1; off < 16; off <<= 1) {
    zpart += __shfl_xor(zpart, off, 64);
    aepart += __shfl_xor(aepart, off, 64);
  }
  float dinv = (e > s) ? 1.0f / (float)(e - s) : 1.0f;
  float sl = a_src[n * 4 + hw] + based + aepart * dinv;
  sl = (sl >= 0.f) ? sl : NEG_SLOPE * sl;
  float wself = __expf(sl);
  half4v sv = xh4[(size_t)n * 64 + t];
  a0 += wself * (float)sv[0];
  a1 += wself * (float)sv[1];
  a2 += wself * (float)sv[2];
  a3 += wself * (float)sv[3];
  float zinv = 1.0f / (zpart + wself + 1e-16f);

  half4v ho;
  ho[0] = (_Float16)fmaxf((a0 * zinv + cb[ch + 0]) * inv_std * gm[ch + 0] + bt[ch + 0], 0.f);
  ho[1] = (_Float16)fmaxf((a1 * zinv + cb[ch + 1]) * inv_std * gm[ch + 1] + bt[ch + 1], 0.f);
  ho[2] = (_Float16)fmaxf((a2 * zinv + cb[ch + 2]) * inv_std * gm[ch + 2] + bt[ch + 2], 0.f);
  ho[3] = (_Float16)fmaxf((a3 * zinv + cb[ch + 3]) * inv_std * gm[ch + 3] + bt[ch + 3], 0.f);
  *(half4v*)&hout[(size_t)n * HD + ch] = ho;
}

// ---------------------------------------------------------------------------
// Global mean pool over sorted batch ids (h fp16). Grid (G, 2), 128 ch.
// ---------------------------------------------------------------------------
__global__ __launch_bounds__(128) void pool_kernel(
    const _Float16* __restrict__ h, const int* __restrict__ batch,
    float* __restrict__ out, int N) {
  int g = blockIdx.x;
  int ch = blockIdx.y * 128 + threadIdx.x;
  __shared__ int s_lo, s_hi;
  if (threadIdx.x == 0) {
    int lo = 0, hi = N;
    while (lo < hi) { int mid = (lo + hi) >> 1; if (batch[mid] < g) lo = mid + 1; else hi = mid; }
    s_lo = lo;
    lo = 0; hi = N;
    while (lo < hi) { int mid = (lo + hi) >> 1; if (batch[mid] < g + 1) lo = mid + 1; else hi = mid; }
    s_hi = lo;
  }
  __syncthreads();
  int lo = s_lo, hi = s_hi;
  float acc = 0.f;
  for (int n = lo; n < hi; ++n) acc += (float)h[(size_t)n * HD + ch];
  int cnt = hi - lo;
  out[(size_t)g * HD + ch] = acc / (float)(cnt > 0 ? cnt : 1);
}

// ---------------------------------------------------------------------------
extern "C" void kernel_launch(void* const* d_in, const int* in_sizes, int n_in,
                              void* d_out, int out_size, void* d_ws, size_t ws_size,
                              hipStream_t stream) {
  const float* x = (const float*)d_in[0];
  const int* ei = (const int*)d_in[1];
  const float* edge_attr = (const float*)d_in[2];
  const int* batch = (const int*)d_in[3];
  const float* Wn = (const float*)d_in[4];
  const float* bn_b = (const float*)d_in[5];
  const float* We = (const float*)d_in[6];
  const float* be_b = (const float*)d_in[7];
  const float* lin_w = (const float*)d_in[8];
  const float* att_src = (const float*)d_in[9];
  const float* att_dst = (const float*)d_in[10];
  const float* lin_edge_w = (const float*)d_in[11];
  const float* att_edge = (const float*)d_in[12];
  const float* conv_bias = (const float*)d_in[13];
  const float* gamma = (const float*)d_in[14];
  const float* beta = (const float*)d_in[15];

  const int N = in_sizes[3];
  const int E = in_sizes[1] / 2;
  const int G = out_size / HD;
  const int* row = ei;
  const int* col = ei + E;

  char* ws = (char*)d_ws;
  size_t off = 0;
  auto alloc = [&](size_t bytes) -> char* {
    char* p = ws + off;
    off += (bytes + 255) & ~(size_t)255;
    return p;
  };
  _Float16* h = (_Float16*)alloc((size_t)N * HD * 2);
  __half* xh_h = (__half*)alloc((size_t)N * HD * 2);
  float* a_src = (float*)alloc((size_t)N * NHEAD * 4);
  float* a_dst = (float*)alloc((size_t)N * NHEAD * 4);
  unsigned* ecsr = (unsigned*)alloc((size_t)E * 32);   // 32B record per edge
  int* deg = (int*)alloc((size_t)N * 4);
  int* row_start = (int*)alloc((size_t)(N + 1) * 4);
  int* cursor = (int*)alloc((size_t)N * 4);
  int* tsum = (int*)alloc(4096);
  int* toff = (int*)alloc(4096);
  float* Wc = (float*)alloc(64 * 4);
  float* bc = (float*)alloc(16 * 4);
  _Float16* Bf_hi = (_Float16*)alloc((size_t)NLAYER * HD * HD * 2);

  (void)hipMemsetAsync(deg, 0, (size_t)N * 4, stream);
  (void)hipMemsetAsync(cursor, 0, (size_t)N * 4, stream);

  int embedBlocks = (N + 7) / 8;
  int countBlocks = (E + 255) / 256;
  embed_count_kernel<<<embedBlocks + countBlocks, 256, 0, stream>>>(
      x, Wn, bn_b, h, N, col, deg, E, embedBlocks);
  wc_bfrag_kernel<<<12 + NLAYER * 32, 256, 0, stream>>>(
      lin_edge_w, att_edge, We, be_b, Wc, bc, lin_w, Bf_hi);
  int T = (N + 255) / 256;
  tile_sums_kernel<<<T, 256, 0, stream>>>(deg, tsum, N);
  scan_tsums_kernel<<<1, 64, 0, stream>>>(tsum, toff, T);
  scan_local_kernel<<<T, 256, 0, stream>>>(deg, toff, row_start, N, E);
  scatter_csr_ae_kernel<<<(E + 255) / 256, 256, 0, stream>>>(
      row, col, edge_attr, row_start, cursor, Wc, bc, ecsr, E);

  const float inv_std = 1.0f / sqrtf(1.0f + 1e-5f);
  for (int l = 0; l < NLAYER; ++l) {
    dim3 gg((N + 127) / 128, 2);
    mfma_gemm_fused_kernel<<<gg, 512, 0, stream>>>(
        h, Bf_hi + (size_t)l * HD * HD,
        att_src + l * HD, att_dst + l * HD, xh_h, a_src, a_dst, N);
    fused_aggregate_kernel<<<(N + 3) / 4, 256, 0, stream>>>(
        xh_h, ecsr, row_start, l, a_src, a_dst,
        conv_bias + l * HD, gamma + l * HD, beta + l * HD, inv_std, h, N);
  }
  dim3 pg(G, 2);
  pool_kernel<<<pg, 128, 0, stream>>>(h, batch, (float*)d_out, N);
}

// Round 22
// 506.926 us; speedup vs baseline: 1.0423x; 1.0423x over previous
//
#include <hip/hip_runtime.h>
#include <hip/hip_fp16.h>
#include <math.h>

#define HD 256
#define NHEAD 4
#define CH 64
#define NLAYER 3
#define NEG_SLOPE 0.2f

typedef __attribute__((ext_vector_type(8))) _Float16 half8;
typedef __attribute__((ext_vector_type(4))) _Float16 half4v;
typedef __attribute__((ext_vector_type(4))) float float4v;
typedef __attribute__((ext_vector_type(4))) unsigned uint4v;

// ---------------------------------------------------------------------------
// FUSED: node embed (blocks [0, embedBlocks)) + degree count (rest).
// h0 = x @ Wn + bn_b  (fp16 out);  deg[col[e]]++ via atomics.
// ---------------------------------------------------------------------------
__global__ __launch_bounds__(256) void embed_count_kernel(
    const float* __restrict__ x, const float* __restrict__ Wn,
    const float* __restrict__ bn_b, _Float16* __restrict__ h, int N,
    const int* __restrict__ col, int* __restrict__ deg, int E,
    int embedBlocks) {
  int tid = threadIdx.x;
  if ((int)blockIdx.x < embedBlocks) {
    int base = blockIdx.x * 8;
    __shared__ float xs[8][9];
    int nn = N - base;
    if (nn > 8) nn = 8;
    if (tid < nn * 9) xs[tid / 9][tid % 9] = x[(size_t)base * 9 + tid];
    __syncthreads();
    float b = bn_b[tid];
    for (int i = 0; i < nn; ++i) {
      float v = b;
#pragma unroll
      for (int k = 0; k < 9; ++k) v += xs[i][k] * Wn[k * HD + tid];
      h[(size_t)(base + i) * HD + tid] = (_Float16)v;
    }
  } else {
    int e = (blockIdx.x - embedBlocks) * 256 + tid;
    if (e < E) atomicAdd(&deg[col[e]], 1);
  }
}

// ---------------------------------------------------------------------------
// FUSED: precompute_wc (blocks 0..11) + conv_bfrag (blocks 12..).
// ---------------------------------------------------------------------------
__global__ __launch_bounds__(256) void wc_bfrag_kernel(
    const float* __restrict__ lin_edge_w, const float* __restrict__ att_edge,
    const float* __restrict__ We, const float* __restrict__ be_b,
    float* __restrict__ Wc, float* __restrict__ bc,
    const float* __restrict__ lin_w, _Float16* __restrict__ Bf_hi) {
  int tid = threadIdx.x;
  if (blockIdx.x < 12) {
    int lh = blockIdx.x;           // l*4+hh
    int l = lh >> 2, hh = lh & 3;
    __shared__ float weff[256];
    int j = tid;
    const float* lw = lin_edge_w + (size_t)l * HD * HD + (size_t)j * HD + hh * CH;
    const float* ae = att_edge + l * HD + hh * CH;
    float s = 0.f;
#pragma unroll 8
    for (int c = 0; c < CH; ++c) s += lw[c] * ae[c];
    weff[j] = s;
    __syncthreads();
    if (j < 5) {
      float acc = 0.f;
      for (int t = 0; t < 256; ++t) acc += We[j * HD + t] * weff[t];
      Wc[j * 12 + lh] = acc;
    } else if (j == 5) {
      float acc = 0.f;
      for (int t = 0; t < 256; ++t) acc += be_b[t] * weff[t];
      bc[lh] = acc;
    }
  } else {
    int bid = (blockIdx.x - 12) * 4 + (tid >> 6);  // l*128 + kt*16 + ntg
    int l = bid >> 7;
    int kt = (bid >> 4) & 7, ntg = bid & 15;
    int lane = tid & 63;
    const float* B = lin_w + (size_t)l * HD * HD;
    size_t base = ((size_t)bid * 64 + lane) * 8;
    int k0 = kt * 32 + (lane >> 4) * 8;
    int n = ((ntg >= 8) ? 128 : 0) + (lane & 15) * 8 + (ntg & 7);
#pragma unroll
    for (int j = 0; j < 8; ++j) {
      Bf_hi[base + j] = (_Float16)B[(size_t)(k0 + j) * HD + n];
    }
  }
}

// ---------------------------------------------------------------------------
// CSR scan kernels
// ---------------------------------------------------------------------------
__global__ __launch_bounds__(256) void tile_sums_kernel(
    const int* __restrict__ deg, int* __restrict__ tsum, int N) {
  __shared__ int red[256];
  int i = blockIdx.x * 256 + threadIdx.x;
  red[threadIdx.x] = (i < N) ? deg[i] : 0;
  __syncthreads();
  for (int off = 128; off > 0; off >>= 1) {
    if (threadIdx.x < off) red[threadIdx.x] += red[threadIdx.x + off];
    __syncthreads();
  }
  if (threadIdx.x == 0) tsum[blockIdx.x] = red[0];
}

__global__ __launch_bounds__(64) void scan_tsums_kernel(
    const int* __restrict__ tsum, int* __restrict__ toff, int T) {
  int lane = threadIdx.x;
  int carry = 0;
  for (int base = 0; base < T; base += 64) {
    int i = base + lane;
    int orig = (i < T) ? tsum[i] : 0;
    int v = orig;
#pragma unroll
    for (int off = 1; off < 64; off <<= 1) {
      int t = __shfl_up(v, off, 64);
      if (lane >= off) v += t;
    }
    if (i < T) toff[i] = carry + v - orig;
    carry += __shfl(v, 63, 64);
  }
}

__global__ __launch_bounds__(256) void scan_local_kernel(
    const int* __restrict__ deg, const int* __restrict__ toff,
    int* __restrict__ row_start, int N, int E) {
  __shared__ int buf[256];
  int i = blockIdx.x * 256 + threadIdx.x;
  int v = (i < N) ? deg[i] : 0;
  buf[threadIdx.x] = v;
  __syncthreads();
  for (int off = 1; off < 256; off <<= 1) {
    int t = (threadIdx.x >= off) ? buf[threadIdx.x - off] : 0;
    __syncthreads();
    buf[threadIdx.x] += t;
    __syncthreads();
  }
  if (i < N) row_start[i] = toff[blockIdx.x] + buf[threadIdx.x] - v;
  if (blockIdx.x == 0 && threadIdx.x == 0) row_start[N] = E;
}

// ---------------------------------------------------------------------------
// CSR scatter writing ONE 32B record per edge (PLAIN stores — records are
// re-read 3x by aggregate, so they must stay L2-resident; R21's nt-store
// bypass cost aggregate ~5 us/dispatch): word0 = src row,
// words 1..6 = 12 x fp16 a_e, word7 pad.
// ---------------------------------------------------------------------------
__global__ __launch_bounds__(256) void scatter_csr_ae_kernel(
    const int* __restrict__ row, const int* __restrict__ col,
    const float* __restrict__ edge_attr, const int* __restrict__ row_start,
    int* __restrict__ cursor, const float* __restrict__ Wc,
    const float* __restrict__ bc, unsigned* __restrict__ ecsr, int E) {
  __shared__ float sWc[60];
  __shared__ float sbc[12];
  int t = threadIdx.x;
  if (t < 60) sWc[t] = Wc[t];
  if (t < 12) sbc[t] = bc[t];
  __syncthreads();
  int e = blockIdx.x * 256 + t;
  if (e >= E) return;
  int c = col[e];
  int p = atomicAdd(&cursor[c], 1);
  float ea[5];
#pragma unroll
  for (int k = 0; k < 5; ++k) ea[k] = edge_attr[(size_t)e * 5 + k];
  unsigned rec[8];
  rec[0] = (unsigned)row[e];
#pragma unroll
  for (int l = 0; l < NLAYER; ++l) {
    float av[NHEAD];
#pragma unroll
    for (int hh = 0; hh < NHEAD; ++hh) {
      int lh = l * NHEAD + hh;
      float s = sbc[lh];
#pragma unroll
      for (int k = 0; k < 5; ++k) s += ea[k] * sWc[k * 12 + lh];
      av[hh] = s;
    }
    __half2 p0 = __floats2half2_rn(av[0], av[1]);
    __half2 p1 = __floats2half2_rn(av[2], av[3]);
    rec[1 + 2 * l] = *(unsigned*)&p0;
    rec[2 + 2 * l] = *(unsigned*)&p1;
  }
  rec[7] = 0u;
  int slot = row_start[c] + p;
  uint4v* dst = (uint4v*)(ecsr + (size_t)slot * 8);
  uint4v v0 = {rec[0], rec[1], rec[2], rec[3]};
  uint4v v1 = {rec[4], rec[5], rec[6], rec[7]};
  dst[0] = v0;
  dst[1] = v1;
}

// ---------------------------------------------------------------------------
// MFMA GEMM — A fp16: direct half8 load, 1 MFMA per (kt,nt).
// Head-split grid y, 8KB LDS B-stage.
// ---------------------------------------------------------------------------
__global__ __launch_bounds__(512) void mfma_gemm_fused_kernel(
    const _Float16* __restrict__ A, const _Float16* __restrict__ Bf_hi,
    const float* __restrict__ att_s, const float* __restrict__ att_d,
    __half* __restrict__ xh_h, float* __restrict__ a_src,
    float* __restrict__ a_dst, int N) {
  __shared__ _Float16 sBh[4096];  // 8 KB: kt-slice of this block's col half
  const int tid = threadIdx.x;
  const int wave = tid >> 6, lane = tid & 63;
  const int m = lane & 15, quad = lane >> 4;
  const int y = blockIdx.y;
  const int rowbase = blockIdx.x * 128 + wave * 16;
  const int arow = rowbase + m;
  const int arowc = (arow < N) ? arow : (N - 1);

  float4v acc[8];
#pragma unroll
  for (int nt = 0; nt < 8; ++nt) acc[nt] = (float4v){0.f, 0.f, 0.f, 0.f};

  for (int kt = 0; kt < 8; ++kt) {
    __syncthreads();  // previous iteration's LDS reads done
    {
      const float4* gh = (const float4*)(Bf_hi + ((size_t)kt * 16 + y * 8) * 512);
      ((float4*)sBh)[tid] = gh[tid];
    }
    half8 a = *(const half8*)(A + (size_t)arowc * HD + kt * 32 + quad * 8);
    __syncthreads();  // staging complete
#pragma unroll
    for (int nt = 0; nt < 8; ++nt) {
      half8 bhi = *(const half8*)&sBh[nt * 512 + lane * 8];
      acc[nt] = __builtin_amdgcn_mfma_f32_16x16x32_f16(a, bhi, acc[nt], 0, 0, 0);
    }
  }

  // lane's 8 cols: y*128 + m*8 + nt — all in head hh = y*2 + (m>>3)
  const int hh = y * 2 + (m >> 3);
  const int colbase = y * 128 + m * 8;
  float ats[8], atd[8];
#pragma unroll
  for (int nt = 0; nt < 8; ++nt) {
    ats[nt] = att_s[colbase + nt];
    atd[nt] = att_d[colbase + nt];
  }
  _Float16* xf = (_Float16*)xh_h;
#pragma unroll
  for (int r = 0; r < 4; ++r) {
    int orow = rowbase + quad * 4 + r;
    bool valid = orow < N;
    float ps = 0.f, pd = 0.f;
    half8 h0;
#pragma unroll
    for (int nt = 0; nt < 8; ++nt) {
      h0[nt] = (_Float16)acc[nt][r];
      ps += acc[nt][r] * ats[nt];
      pd += acc[nt][r] * atd[nt];
    }
    if (valid) {
      *(half8*)(xf + (size_t)orow * HD + colbase) = h0;
    }
    ps += __shfl_xor(ps, 1, 64);
    ps += __shfl_xor(ps, 2, 64);
    ps += __shfl_xor(ps, 4, 64);
    pd += __shfl_xor(pd, 1, 64);
    pd += __shfl_xor(pd, 2, 64);
    pd += __shfl_xor(pd, 4, 64);
    if (valid && (m & 7) == 0) {
      a_src[(size_t)orow * NHEAD + hh] = ps;
      a_dst[(size_t)orow * NHEAD + hh] = pd;
    }
  }
}

// ---------------------------------------------------------------------------
// SINGLE-PASS fused softmax + gather-aggregate over 32B edge records.
// (R19 counters: ~6.2 TB/s effective — at the measured streaming ceiling.)
// ---------------------------------------------------------------------------
__global__ __launch_bounds__(256) void fused_aggregate_kernel(
    const __half* __restrict__ xh_h, const unsigned* __restrict__ ecsr,
    const int* __restrict__ row_start, int lsel,
    const float* __restrict__ a_src, const float* __restrict__ a_dst,
    const float* __restrict__ cb, const float* __restrict__ gm,
    const float* __restrict__ bt, float inv_std, _Float16* __restrict__ hout,
    int N) {
  int tid = threadIdx.x;
  int n = blockIdx.x * 4 + (tid >> 6);
  if (n >= N) return;
  int lane = tid & 63;
  int s = row_start[n], e = row_start[n + 1];

  const int hw = lane >> 4;        // head (same for weights and channels)
  const int eidx = lane & 15;
  const int t = lane;              // half4 index (4 ch/lane)
  const int ch = t * 4;
  const half4v* xh4 = (const half4v*)xh_h;
  const float based = a_dst[n * 4 + hw];
  const int aofs = 1 + 2 * lsel + (hw >> 1);
  const bool hi_half = (hw & 1);

  float a0 = 0.f, a1 = 0.f, a2 = 0.f, a3 = 0.f;
  float zpart = 0.f, aepart = 0.f;

  const int base_src = lane & 48;
  for (int chunk = s; chunk < e; chunk += 16) {
    int myedge = chunk + eidx;
    int r_my = 0;
    float w_my = 0.f;
    if (myedge < e) {
      const unsigned* rp = ecsr + (size_t)myedge * 8;
      r_my = (int)rp[0];
      unsigned aw = rp[aofs];
      __half2 h2 = *(__half2*)&aw;
      float ae = hi_half ? __high2float(h2) : __low2float(h2);
      float lg = a_src[r_my * 4 + hw] + based + ae;
      lg = (lg >= 0.f) ? lg : NEG_SLOPE * lg;
      w_my = __expf(lg);
      zpart += w_my;
      aepart += ae;
    }
#pragma unroll
    for (int u = 0; u < 16; ++u) {
      float w = __shfl(w_my, base_src + u, 64);
      int ru = __shfl(r_my, base_src + u, 64);
      half4v xv = xh4[(size_t)ru * 64 + t];
      a0 += w * (float)xv[0];
      a1 += w * (float)xv[1];
      a2 += w * (float)xv[2];
      a3 += w * (float)xv[3];
    }
  }
#pragma unroll
  for (int off = 1; off < 16; off <<= 1) {
    zpart += __shfl_xor(zpart, off, 64);
    aepart += __shfl_xor(aepart, off, 64);
  }
  float dinv = (e > s) ? 1.0f / (float)(e - s) : 1.0f;
  float sl = a_src[n * 4 + hw] + based + aepart * dinv;
  sl = (sl >= 0.f) ? sl : NEG_SLOPE * sl;
  float wself = __expf(sl);
  half4v sv = xh4[(size_t)n * 64 + t];
  a0 += wself * (float)sv[0];
  a1 += wself * (float)sv[1];
  a2 += wself * (float)sv[2];
  a3 += wself * (float)sv[3];
  float zinv = 1.0f / (zpart + wself + 1e-16f);

  half4v ho;
  ho[0] = (_Float16)fmaxf((a0 * zinv + cb[ch + 0]) * inv_std * gm[ch + 0] + bt[ch + 0], 0.f);
  ho[1] = (_Float16)fmaxf((a1 * zinv + cb[ch + 1]) * inv_std * gm[ch + 1] + bt[ch + 1], 0.f);
  ho[2] = (_Float16)fmaxf((a2 * zinv + cb[ch + 2]) * inv_std * gm[ch + 2] + bt[ch + 2], 0.f);
  ho[3] = (_Float16)fmaxf((a3 * zinv + cb[ch + 3]) * inv_std * gm[ch + 3] + bt[ch + 3], 0.f);
  *(half4v*)&hout[(size_t)n * HD + ch] = ho;
}

// ---------------------------------------------------------------------------
// Global mean pool over sorted batch ids (h fp16). Grid (G, 2), 128 ch.
// ---------------------------------------------------------------------------
__global__ __launch_bounds__(128) void pool_kernel(
    const _Float16* __restrict__ h, const int* __restrict__ batch,
    float* __restrict__ out, int N) {
  int g = blockIdx.x;
  int ch = blockIdx.y * 128 + threadIdx.x;
  __shared__ int s_lo, s_hi;
  if (threadIdx.x == 0) {
    int lo = 0, hi = N;
    while (lo < hi) { int mid = (lo + hi) >> 1; if (batch[mid] < g) lo = mid + 1; else hi = mid; }
    s_lo = lo;
    lo = 0; hi = N;
    while (lo < hi) { int mid = (lo + hi) >> 1; if (batch[mid] < g + 1) lo = mid + 1; else hi = mid; }
    s_hi = lo;
  }
  __syncthreads();
  int lo = s_lo, hi = s_hi;
  float acc = 0.f;
  for (int n = lo; n < hi; ++n) acc += (float)h[(size_t)n * HD + ch];
  int cnt = hi - lo;
  out[(size_t)g * HD + ch] = acc / (float)(cnt > 0 ? cnt : 1);
}

// ---------------------------------------------------------------------------
extern "C" void kernel_launch(void* const* d_in, const int* in_sizes, int n_in,
                              void* d_out, int out_size, void* d_ws, size_t ws_size,
                              hipStream_t stream) {
  const float* x = (const float*)d_in[0];
  const int* ei = (const int*)d_in[1];
  const float* edge_attr = (const float*)d_in[2];
  const int* batch = (const int*)d_in[3];
  const float* Wn = (const float*)d_in[4];
  const float* bn_b = (const float*)d_in[5];
  const float* We = (const float*)d_in[6];
  const float* be_b = (const float*)d_in[7];
  const float* lin_w = (const float*)d_in[8];
  const float* att_src = (const float*)d_in[9];
  const float* att_dst = (const float*)d_in[10];
  const float* lin_edge_w = (const float*)d_in[11];
  const float* att_edge = (const float*)d_in[12];
  const float* conv_bias = (const float*)d_in[13];
  const float* gamma = (const float*)d_in[14];
  const float* beta = (const float*)d_in[15];

  const int N = in_sizes[3];
  const int E = in_sizes[1] / 2;
  const int G = out_size / HD;
  const int* row = ei;
  const int* col = ei + E;

  char* ws = (char*)d_ws;
  size_t off = 0;
  auto alloc = [&](size_t bytes) -> char* {
    char* p = ws + off;
    off += (bytes + 255) & ~(size_t)255;
    return p;
  };
  _Float16* h = (_Float16*)alloc((size_t)N * HD * 2);
  __half* xh_h = (__half*)alloc((size_t)N * HD * 2);
  float* a_src = (float*)alloc((size_t)N * NHEAD * 4);
  float* a_dst = (float*)alloc((size_t)N * NHEAD * 4);
  unsigned* ecsr = (unsigned*)alloc((size_t)E * 32);   // 32B record per edge
  int* deg = (int*)alloc((size_t)N * 4);
  int* row_start = (int*)alloc((size_t)(N + 1) * 4);
  int* cursor = (int*)alloc((size_t)N * 4);
  int* tsum = (int*)alloc(4096);
  int* toff = (int*)alloc(4096);
  float* Wc = (float*)alloc(64 * 4);
  float* bc = (float*)alloc(16 * 4);
  _Float16* Bf_hi = (_Float16*)alloc((size_t)NLAYER * HD * HD * 2);

  (void)hipMemsetAsync(deg, 0, (size_t)N * 4, stream);
  (void)hipMemsetAsync(cursor, 0, (size_t)N * 4, stream);

  int embedBlocks = (N + 7) / 8;
  int countBlocks = (E + 255) / 256;
  embed_count_kernel<<<embedBlocks + countBlocks, 256, 0, stream>>>(
      x, Wn, bn_b, h, N, col, deg, E, embedBlocks);
  wc_bfrag_kernel<<<12 + NLAYER * 32, 256, 0, stream>>>(
      lin_edge_w, att_edge, We, be_b, Wc, bc, lin_w, Bf_hi);
  int T = (N + 255) / 256;
  tile_sums_kernel<<<T, 256, 0, stream>>>(deg, tsum, N);
  scan_tsums_kernel<<<1, 64, 0, stream>>>(tsum, toff, T);
  scan_local_kernel<<<T, 256, 0, stream>>>(deg, toff, row_start, N, E);
  scatter_csr_ae_kernel<<<(E + 255) / 256, 256, 0, stream>>>(
      row, col, edge_attr, row_start, cursor, Wc, bc, ecsr, E);

  const float inv_std = 1.0f / sqrtf(1.0f + 1e-5f);
  for (int l = 0; l < NLAYER; ++l) {
    dim3 gg((N + 127) / 128, 2);
    mfma_gemm_fused_kernel<<<gg, 512, 0, stream>>>(
        h, Bf_hi + (size_t)l * HD * HD,
        att_src + l * HD, att_dst + l * HD, xh_h, a_src, a_dst, N);
    fused_aggregate_kernel<<<(N + 3) / 4, 256, 0, stream>>>(
        xh_h, ecsr, row_start, l, a_src, a_dst,
        conv_bias + l * HD, gamma + l * HD, beta + l * HD, inv_std, h, N);
  }
  dim3 pg(G, 2);
  pool_kernel<<<pg, 128, 0, stream>>>(h, batch, (float*)d_out, N);
}